// Round 9
// baseline (187.423 us; speedup 1.0000x reference)
//
#include <hip/hip_runtime.h>
#include <math.h>

#define B 256
#define D 512
#define S 196
#define SQ 49    // float4 quads per 196-float row
#define NCH 8

// ---------------- K1: partial GEMM (R4 proven, ~6 us).
// Grid 512 = (ce 0..7) x (dhalf 0..1) x (batch-octet 0..31), 2 blocks/CU.
// gpart[(b*8+ce)*D + d] = sum_{e in chunk ce} u[b,e]*W[e,d], u = ctrl*w_attn.
__global__ __launch_bounds__(256) void k_gemm2(
    const float* __restrict__ ctrl, const float* __restrict__ w_attn,
    const float* __restrict__ W, float* __restrict__ gpart) {
    __shared__ float u_s[64][8];          // [e_local][batch j]
    const int ce = blockIdx.x >> 6;
    const int dh = (blockIdx.x >> 5) & 1;
    const int b0 = (blockIdx.x & 31) * 8;
    const int t = threadIdx.x;
    const int d = dh * 256 + t;
#pragma unroll
    for (int k = t; k < 512; k += 256) {
        const int j = k & 7, el = k >> 3;
        const int e = ce * 64 + el;
        u_s[el][j] = ctrl[(size_t)(b0 + j) * D + e] * w_attn[e];
    }
    __syncthreads();
    float a[8];
#pragma unroll
    for (int j = 0; j < 8; ++j) a[j] = 0.f;
    for (int e0 = 0; e0 < 64; e0 += 4) {
        float wv[4];
#pragma unroll
        for (int i = 0; i < 4; ++i)
            wv[i] = W[(size_t)(ce * 64 + e0 + i) * D + d];
#pragma unroll
        for (int i = 0; i < 4; ++i) {
            const float4 ua = *(const float4*)&u_s[e0 + i][0];
            const float4 ub = *(const float4*)&u_s[e0 + i][4];
            a[0] += ua.x * wv[i]; a[1] += ua.y * wv[i];
            a[2] += ua.z * wv[i]; a[3] += ua.w * wv[i];
            a[4] += ub.x * wv[i]; a[5] += ub.y * wv[i];
            a[6] += ub.z * wv[i]; a[7] += ub.w * wv[i];
        }
    }
#pragma unroll
    for (int j = 0; j < 8; ++j)
        gpart[((size_t)(b0 + j) * NCH + ce) * D + d] = a[j];
}

// ---------------- K2: partial logits, tuned for streaming. Grid 2048 x 256.
// launch_bounds(256,4): 4 blocks/CU, 128-VGPR budget so 16 float4 loads can
// be held in flight. Wave w streams its 16 rows as FOUR adjacent-row chains
// (4 x 784B in flight per wave; ~49 KB/CU outstanding = 2x Little's law).
// First 4-row group is hoisted ABOVE the p-head so HBM starts at cycle 0.
// NO barriers inside the streaming loop. p-head uses all 4 waves.
__global__ __launch_bounds__(256, 4) void k_logits(
    const float* __restrict__ kb, const float* __restrict__ gpart,
    const float* __restrict__ mem, const float* __restrict__ ctrl,
    const float* __restrict__ w_attn, float* __restrict__ rai_part) {
    __shared__ float ph[4][64];
    __shared__ float p_s[64];
    __shared__ float part[4][S];
    const int bid = blockIdx.x;
    const int b = bid >> 3, c = bid & 7;
    const int t = threadIdx.x;
    const int w = t >> 6, l = t & 63;
    const float* base = kb + (size_t)b * D * S + (size_t)c * 64 * S;
    const int r0 = w * 16;

    // hoisted first 4-row group (stream starts before the head)
    float4 h0, h1, h2, h3;
    if (l < SQ) {
        h0 = *(const float4*)(base + (size_t)(r0 + 0) * S + 4 * l);
        h1 = *(const float4*)(base + (size_t)(r0 + 1) * S + 4 * l);
        h2 = *(const float4*)(base + (size_t)(r0 + 2) * S + 4 * l);
        h3 = *(const float4*)(base + (size_t)(r0 + 3) * S + 4 * l);
    }
    // p head: all 4 waves each fold 2 gpart chunks
    {
        const int d = c * 64 + l;
        ph[w][l] = gpart[((size_t)b * NCH + w) * D + d] +
                   gpart[((size_t)b * NCH + w + 4) * D + d];
    }
    __syncthreads();
    if (t < 64) {
        const int d = c * 64 + t;
        const float g = (ph[0][t] + ph[1][t]) + (ph[2][t] + ph[3][t]);
        p_s[t] = mem[(size_t)b * D + d] * g +
                 ctrl[(size_t)b * D + d] * w_attn[d];
    }
    __syncthreads();

    if (l < SQ) {
        float4 a0, a1, a2, a3;
        {   // chain ch covers rows {r0+ch, r0+4+ch, r0+8+ch, r0+12+ch}
            const float p0 = p_s[r0 + 0], p1 = p_s[r0 + 1];
            const float p2 = p_s[r0 + 2], p3 = p_s[r0 + 3];
            a0.x = p0 * h0.x; a0.y = p0 * h0.y; a0.z = p0 * h0.z; a0.w = p0 * h0.w;
            a1.x = p1 * h1.x; a1.y = p1 * h1.y; a1.z = p1 * h1.z; a1.w = p1 * h1.w;
            a2.x = p2 * h2.x; a2.y = p2 * h2.y; a2.z = p2 * h2.z; a2.w = p2 * h2.w;
            a3.x = p3 * h3.x; a3.y = p3 * h3.y; a3.z = p3 * h3.z; a3.w = p3 * h3.w;
        }
#pragma unroll
        for (int i = 1; i < 4; ++i) {
            const int r = r0 + 4 * i;
            const float4 v0 = *(const float4*)(base + (size_t)(r + 0) * S + 4 * l);
            const float4 v1 = *(const float4*)(base + (size_t)(r + 1) * S + 4 * l);
            const float4 v2 = *(const float4*)(base + (size_t)(r + 2) * S + 4 * l);
            const float4 v3 = *(const float4*)(base + (size_t)(r + 3) * S + 4 * l);
            const float p0 = p_s[r + 0], p1 = p_s[r + 1];
            const float p2 = p_s[r + 2], p3 = p_s[r + 3];
            a0.x += p0 * v0.x; a0.y += p0 * v0.y; a0.z += p0 * v0.z; a0.w += p0 * v0.w;
            a1.x += p1 * v1.x; a1.y += p1 * v1.y; a1.z += p1 * v1.z; a1.w += p1 * v1.w;
            a2.x += p2 * v2.x; a2.y += p2 * v2.y; a2.z += p2 * v2.z; a2.w += p2 * v2.w;
            a3.x += p3 * v3.x; a3.y += p3 * v3.y; a3.z += p3 * v3.z; a3.w += p3 * v3.w;
        }
        part[w][4 * l + 0] = (a0.x + a1.x) + (a2.x + a3.x);
        part[w][4 * l + 1] = (a0.y + a1.y) + (a2.y + a3.y);
        part[w][4 * l + 2] = (a0.z + a1.z) + (a2.z + a3.z);
        part[w][4 * l + 3] = (a0.w + a1.w) + (a2.w + a3.w);
    }
    __syncthreads();
    if (t < S)
        rai_part[(size_t)bid * S + t] =
            (part[0][t] + part[1][t]) + (part[2][t] + part[3][t]);
}

// ---------------- K3: softmax head + weighted sum, same streaming recipe.
// Grid 2048 x 256, 4 blocks/CU. kb re-read is L3-resident (102.8 MB < 256 MB).
// First 4-row group hoisted above the softmax head; 4 chains; body barrier-
// free; [64][49] LDS transpose-reduce (odd stride -> <=2-way banks = free)
// -> coalesced 256B store.
__global__ __launch_bounds__(256, 4) void k_wsum(
    const float* __restrict__ kb, const float* __restrict__ rai_part,
    float* __restrict__ out) {
    __shared__ float rvi_s[S];
    __shared__ float redm[4], reds[4];
    __shared__ float plds[64 * SQ];   // 12.5 KB
    __shared__ float red2[4][64];
    const int bid = blockIdx.x;
    const int b = bid >> 3, c = bid & 7;
    const int t = threadIdx.x;
    const int w = t >> 6, l = t & 63;
    const float* base = kb + (size_t)b * D * S + (size_t)c * 64 * S;
    const int r0 = w * 16;

    // hoisted first 4-row group (L3 stream starts before the head)
    float4 h0, h1, h2, h3;
    if (l < SQ) {
        h0 = *(const float4*)(base + (size_t)(r0 + 0) * S + 4 * l);
        h1 = *(const float4*)(base + (size_t)(r0 + 1) * S + 4 * l);
        h2 = *(const float4*)(base + (size_t)(r0 + 2) * S + 4 * l);
        h3 = *(const float4*)(base + (size_t)(r0 + 3) * S + 4 * l);
    }
    // softmax head (redundant per block, cheap and L2-hot)
    float rai = -INFINITY;
    if (t < S) {
        float v = 0.f;
#pragma unroll
        for (int k = 0; k < NCH; ++k)
            v += rai_part[((size_t)b * NCH + k) * S + t];
        rai = v;
    }
    float m = rai;
#pragma unroll
    for (int o = 1; o < 64; o <<= 1) m = fmaxf(m, __shfl_xor(m, o, 64));
    if (l == 0) redm[w] = m;
    __syncthreads();
    m = fmaxf(fmaxf(redm[0], redm[1]), fmaxf(redm[2], redm[3]));
    float ex = (t < S) ? __expf(rai - m) : 0.f;
    float sm = ex;
#pragma unroll
    for (int o = 1; o < 64; o <<= 1) sm += __shfl_xor(sm, o, 64);
    if (l == 0) reds[w] = sm;
    __syncthreads();
    const float li = (reds[0] + reds[1]) + (reds[2] + reds[3]);
    if (t < S) rvi_s[t] = ex / li;
    __syncthreads();

    float4 rv = {0.f, 0.f, 0.f, 0.f};
    if (l < SQ) {
        rv = *(const float4*)&rvi_s[4 * l];
        plds[(r0 + 0) * SQ + l] =
            rv.x * h0.x + rv.y * h0.y + rv.z * h0.z + rv.w * h0.w;
        plds[(r0 + 1) * SQ + l] =
            rv.x * h1.x + rv.y * h1.y + rv.z * h1.z + rv.w * h1.w;
        plds[(r0 + 2) * SQ + l] =
            rv.x * h2.x + rv.y * h2.y + rv.z * h2.z + rv.w * h2.w;
        plds[(r0 + 3) * SQ + l] =
            rv.x * h3.x + rv.y * h3.y + rv.z * h3.z + rv.w * h3.w;
#pragma unroll
        for (int i = 1; i < 4; ++i) {
            const int r = r0 + 4 * i;
            const float4 v0 = *(const float4*)(base + (size_t)(r + 0) * S + 4 * l);
            const float4 v1 = *(const float4*)(base + (size_t)(r + 1) * S + 4 * l);
            const float4 v2 = *(const float4*)(base + (size_t)(r + 2) * S + 4 * l);
            const float4 v3 = *(const float4*)(base + (size_t)(r + 3) * S + 4 * l);
            plds[(r + 0) * SQ + l] =
                rv.x * v0.x + rv.y * v0.y + rv.z * v0.z + rv.w * v0.w;
            plds[(r + 1) * SQ + l] =
                rv.x * v1.x + rv.y * v1.y + rv.z * v1.z + rv.w * v1.w;
            plds[(r + 2) * SQ + l] =
                rv.x * v2.x + rv.y * v2.y + rv.z * v2.z + rv.w * v2.w;
            plds[(r + 3) * SQ + l] =
                rv.x * v3.x + rv.y * v3.y + rv.z * v3.z + rv.w * v3.w;
        }
    }
    __syncthreads();
    {   // transpose-reduce: thread (seg,row) sums its 12-13 quad partials
        const int row = t & 63, seg = t >> 6;
        const int j0 = (seg * SQ) >> 2, j1 = ((seg + 1) * SQ) >> 2;
        float a = 0.f;
        for (int j = j0; j < j1; ++j) a += plds[row * SQ + j];
        red2[seg][row] = a;
    }
    __syncthreads();
    if (t < 64)
        out[(size_t)b * D + c * 64 + t] =
            (red2[0][t] + red2[1][t]) + (red2[2][t] + red2[3][t]);
}

extern "C" void kernel_launch(void* const* d_in, const int* in_sizes, int n_in,
                              void* d_out, int out_size, void* d_ws, size_t ws_size,
                              hipStream_t stream) {
    const float* mem  = (const float*)d_in[0];  // [B, d]
    const float* ctrl = (const float*)d_in[1];  // [B, d]
    const float* kb   = (const float*)d_in[2];  // [B, d, S]
    const float* W    = (const float*)d_in[3];  // [d, d]
    // d_in[4] = b_concat: softmax-invariant, unused
    const float* wat  = (const float*)d_in[5];  // [d]
    float* out = (float*)d_out;                 // [B, d]

    float* gpart    = (float*)d_ws;                  // B*8*D*4 = 4 MB
    float* rai_part = gpart + (size_t)B * NCH * D;   // 2048*S*4 = 1.6 MB

    k_gemm2 <<<512,     256, 0, stream>>>(ctrl, wat, W, gpart);
    k_logits<<<B * NCH, 256, 0, stream>>>(kb, gpart, mem, ctrl, wat, rai_part);
    k_wsum  <<<B * NCH, 256, 0, stream>>>(kb, rai_part, out);
}